// Round 1
// baseline (348.108 us; speedup 1.0000x reference)
//
#include <hip/hip_runtime.h>

typedef float f32x4 __attribute__((ext_vector_type(4)));
typedef short bf16x8 __attribute__((ext_vector_type(8)));

#define SDT_BATCH 65536
#define SDT_PCOLS 1024   // 1023 real cols stored at [1..1023]; col 0 unused

__device__ __forceinline__ unsigned short f2bf(float f) {
    union { float f; unsigned int u; } x; x.f = f;
    unsigned int r = (x.u + 0x7fffu + ((x.u >> 16) & 1u)) >> 16;
    return (unsigned short)r;
}
__device__ __forceinline__ float bf2f(unsigned short h) {
    union { unsigned int u; float f; } x; x.u = ((unsigned int)h) << 16;
    return x.f;
}

// ---------------------------------------------------------------------------
// Kernel 1: p = sigmoid(data @ W_inner^T), stored bf16, shifted +1 column.
// data: [65536][128] f32, Wi: [1023][128] f32, p: [65536][1024] bf16.
// 128x128 tile, K=128 single stage, 4 waves of 64x64, mfma 16x16x32 bf16.
// ---------------------------------------------------------------------------
__global__ __launch_bounds__(256) void k_gemm1(const float* __restrict__ data,
                                               const float* __restrict__ Wi,
                                               unsigned short* __restrict__ p) {
    extern __shared__ char smem[];
    unsigned short (*As)[136] = (unsigned short(*)[136])smem;
    unsigned short (*Bs)[136] = (unsigned short(*)[136])(smem + 128 * 136 * 2);
    const int tid = threadIdx.x;
    const int bm = blockIdx.x, bn = blockIdx.y;

    // stage A (contiguous 128x128 f32), convert to bf16
    const float4* Ag = (const float4*)(data + (size_t)bm * (128 * 128));
#pragma unroll
    for (int i = 0; i < 16; ++i) {
        int idx = tid + 256 * i;
        float4 v = Ag[idx];
        int e = idx << 2, row = e >> 7, col = e & 127;
        ushort4 w; w.x = f2bf(v.x); w.y = f2bf(v.y); w.z = f2bf(v.z); w.w = f2bf(v.w);
        *(ushort4*)&As[row][col] = w;
    }
    // stage B = W_inner rows [bn*128, bn*128+128), zero-pad row 1023
#pragma unroll
    for (int i = 0; i < 16; ++i) {
        int idx = tid + 256 * i;
        int e = idx << 2, row = e >> 7, col = e & 127;
        int gr = bn * 128 + row;
        float4 v = make_float4(0.f, 0.f, 0.f, 0.f);
        if (gr < 1023) v = *(const float4*)(Wi + (size_t)gr * 128 + col);
        ushort4 w; w.x = f2bf(v.x); w.y = f2bf(v.y); w.z = f2bf(v.z); w.w = f2bf(v.w);
        *(ushort4*)&Bs[row][col] = w;
    }
    __syncthreads();

    const int w = tid >> 6, lane = tid & 63;
    const int wm = (w >> 1) * 64, wn = (w & 1) * 64;
    const int lr = lane & 15, lk = (lane >> 4) * 8;
    f32x4 acc[4][4] = {};
#pragma unroll
    for (int ks = 0; ks < 4; ++ks) {
        bf16x8 a[4], b[4];
#pragma unroll
        for (int f = 0; f < 4; ++f)
            a[f] = *(const bf16x8*)&As[wm + f * 16 + lr][ks * 32 + lk];
#pragma unroll
        for (int f = 0; f < 4; ++f)
            b[f] = *(const bf16x8*)&Bs[wn + f * 16 + lr][ks * 32 + lk];
#pragma unroll
        for (int fi = 0; fi < 4; ++fi)
#pragma unroll
            for (int fj = 0; fj < 4; ++fj)
                acc[fi][fj] = __builtin_amdgcn_mfma_f32_16x16x32_bf16(a[fi], b[fj], acc[fi][fj], 0, 0, 0);
    }
    // epilogue: sigmoid -> bf16 -> p (shifted +1)
    const size_t rb = (size_t)bm * 128;
#pragma unroll
    for (int fi = 0; fi < 4; ++fi)
#pragma unroll
        for (int fj = 0; fj < 4; ++fj)
#pragma unroll
            for (int r = 0; r < 4; ++r) {
                int row = wm + fi * 16 + (lane >> 4) * 4 + r;
                int gcol = bn * 128 + wn + fj * 16 + lr;
                float x = acc[fi][fj][r];
                float s = 1.f / (1.f + __expf(-x));
                if (gcol < 1023)
                    p[(rb + row) * SDT_PCOLS + gcol + 1] = f2bf(s);
            }
}

// ---------------------------------------------------------------------------
// Kernel 2: per-32-row block: tree pass (mu ping-pong in LDS), leaf partial
// sums, and out = mu @ W_leaf^T via MFMA.
// p: [65536][1024] bf16 (shifted); Wl: [32][1024] f32; out: [65536][32] f32;
// part: [2048][1024] f32 leaf partial sums.
// ---------------------------------------------------------------------------
__global__ __launch_bounds__(256) void k_tree(const unsigned short* __restrict__ p,
                                              const float* __restrict__ Wl,
                                              float* __restrict__ out,
                                              float* __restrict__ part) {
    extern __shared__ char smem[];
    float (*mA)[516] = (float(*)[516])smem;
    float (*mB)[516] = (float(*)[516])(smem + 32 * 516 * 4);
    unsigned short (*mF)[1032] = (unsigned short(*)[1032])mB; // final bf16 leaves
    const int tid = threadIdx.x;
    const int blk = blockIdx.x;
    const size_t prow0 = (size_t)blk * 32 * SDT_PCOLS;

    // level 0: mu = [p0, 1-p0]
    if (tid < 32) {
        float pv = bf2f(p[prow0 + (size_t)tid * SDT_PCOLS + 1]);
        mA[tid][0] = pv; mA[tid][1] = 1.f - pv;
    }
    __syncthreads();

    // levels 1..8 (parents n = 2^L). in: L odd -> mA, out: L odd -> mB.
    for (int L = 1; L <= 8; ++L) {
        const int n = 1 << L;
        float (*in_)[516]  = (L & 1) ? mA : mB;
        float (*out_)[516] = (L & 1) ? mB : mA;
        if (n <= 4) {
            if (tid < 32 * n) {
                int r = tid >> L, j = tid & (n - 1);
                float mu = in_[r][j];
                float pv = bf2f(p[prow0 + (size_t)r * SDT_PCOLS + n + j]);
                float c0 = mu * pv;
                out_[r][2 * j] = c0; out_[r][2 * j + 1] = mu - c0;
            }
        } else {
            int r = tid >> 3, c8 = tid & 7, cnt = n >> 3;
            const unsigned short* pr = p + prow0 + (size_t)r * SDT_PCOLS + n;
            if (cnt < 4) {
                for (int j = c8 * cnt; j < c8 * cnt + cnt; ++j) {
                    float mu = in_[r][j];
                    float pv = bf2f(pr[j]);
                    float c0 = mu * pv;
                    out_[r][2 * j] = c0; out_[r][2 * j + 1] = mu - c0;
                }
            } else {
                for (int j0 = c8 * cnt; j0 < (c8 + 1) * cnt; j0 += 4) {
                    float4 mu4 = *(const float4*)&in_[r][j0];
                    ushort4 p4 = *(const ushort4*)(pr + j0);
                    float c0 = mu4.x * bf2f(p4.x);
                    float c1 = mu4.y * bf2f(p4.y);
                    float c2 = mu4.z * bf2f(p4.z);
                    float c3 = mu4.w * bf2f(p4.w);
                    float4 lo = make_float4(c0, mu4.x - c0, c1, mu4.y - c1);
                    float4 hi = make_float4(c2, mu4.z - c2, c3, mu4.w - c3);
                    *(float4*)&out_[r][2 * j0] = lo;
                    *(float4*)&out_[r][2 * j0 + 4] = hi;
                }
            }
        }
        __syncthreads();
    }

    // level 9: in mA (512 wide) -> leaves bf16 into mF (mB region)
    {
        int r = tid >> 3, c8 = tid & 7;
        const unsigned short* pr = p + prow0 + (size_t)r * SDT_PCOLS + 512;
        for (int j0 = c8 * 64; j0 < c8 * 64 + 64; j0 += 4) {
            float4 mu4 = *(const float4*)&mA[r][j0];
            ushort4 p4 = *(const ushort4*)(pr + j0);
            float c0 = mu4.x * bf2f(p4.x); float d0 = mu4.x - c0;
            float c1 = mu4.y * bf2f(p4.y); float d1 = mu4.y - c1;
            float c2 = mu4.z * bf2f(p4.z); float d2 = mu4.z - c2;
            float c3 = mu4.w * bf2f(p4.w); float d3 = mu4.w - c3;
            union { unsigned short us[8]; uint4 q; } pk;
            pk.us[0] = f2bf(c0); pk.us[1] = f2bf(d0);
            pk.us[2] = f2bf(c1); pk.us[3] = f2bf(d1);
            pk.us[4] = f2bf(c2); pk.us[5] = f2bf(d2);
            pk.us[6] = f2bf(c3); pk.us[7] = f2bf(d3);
            *(uint4*)&mF[r][2 * j0] = pk.q;
        }
    }
    __syncthreads();

    // leaf partial sums over the 32 rows: thread t owns leaves 4t..4t+3
    {
        float s0 = 0, s1 = 0, s2 = 0, s3 = 0;
#pragma unroll 8
        for (int r = 0; r < 32; ++r) {
            ushort4 v = *(const ushort4*)&mF[r][4 * tid];
            s0 += bf2f(v.x); s1 += bf2f(v.y); s2 += bf2f(v.z); s3 += bf2f(v.w);
        }
        *(float4*)(part + (size_t)blk * 1024 + 4 * tid) = make_float4(s0, s1, s2, s3);
    }

    // GEMM2: out[32][32] = mu(bf16, mF) @ Wl^T. 4 waves split K=1024.
    const int w = tid >> 6, lane = tid & 63;
    const int lr = lane & 15, lkk = (lane >> 4) * 8;
    f32x4 acc[2][2] = {};
#pragma unroll
    for (int ks = 0; ks < 8; ++ks) {
        int kk = w * 256 + ks * 32;
        bf16x8 a[2], b[2];
#pragma unroll
        for (int fi = 0; fi < 2; ++fi)
            a[fi] = *(const bf16x8*)&mF[fi * 16 + lr][kk + lkk];
#pragma unroll
        for (int fj = 0; fj < 2; ++fj) {
            const float* q = Wl + (size_t)(fj * 16 + lr) * 1024 + kk + lkk;
            float4 q0 = *(const float4*)q;
            float4 q1 = *(const float4*)(q + 4);
            union { unsigned short us[8]; bf16x8 v; } ub;
            ub.us[0] = f2bf(q0.x); ub.us[1] = f2bf(q0.y);
            ub.us[2] = f2bf(q0.z); ub.us[3] = f2bf(q0.w);
            ub.us[4] = f2bf(q1.x); ub.us[5] = f2bf(q1.y);
            ub.us[6] = f2bf(q1.z); ub.us[7] = f2bf(q1.w);
            b[fj] = ub.v;
        }
#pragma unroll
        for (int fi = 0; fi < 2; ++fi)
#pragma unroll
            for (int fj = 0; fj < 2; ++fj)
                acc[fi][fj] = __builtin_amdgcn_mfma_f32_16x16x32_bf16(a[fi], b[fj], acc[fi][fj], 0, 0, 0);
    }
    // partial-C reduce across the 4 waves via LDS (reuse mA region)
    float (*pc)[32][32] = (float(*)[32][32])mA;
#pragma unroll
    for (int fi = 0; fi < 2; ++fi)
#pragma unroll
        for (int fj = 0; fj < 2; ++fj)
#pragma unroll
            for (int r = 0; r < 4; ++r)
                pc[w][fi * 16 + (lane >> 4) * 4 + r][fj * 16 + lr] = acc[fi][fj][r];
    __syncthreads();
    {
        int r = tid >> 3, c0 = (tid & 7) * 4;
        float4 s = *(const float4*)&pc[0][r][c0];
        float4 s1 = *(const float4*)&pc[1][r][c0];
        float4 s2 = *(const float4*)&pc[2][r][c0];
        float4 s3 = *(const float4*)&pc[3][r][c0];
        s.x += s1.x + s2.x + s3.x;
        s.y += s1.y + s2.y + s3.y;
        s.z += s1.z + s2.z + s3.z;
        s.w += s1.w + s2.w + s3.w;
        *(float4*)(out + ((size_t)blk * 32 + r) * 32 + c0) = s;
    }
}

// ---------------------------------------------------------------------------
// Kernel 3: Sleaf[leaf] = sum over 2048 block partials.
// grid 64 blocks x 16 leaves each.
// ---------------------------------------------------------------------------
__global__ __launch_bounds__(256) void k_reduce(const float* __restrict__ part,
                                                float* __restrict__ Sleaf) {
    __shared__ float red[256];
    int t = threadIdx.x;
    int leaf0 = blockIdx.x * 16;
    int lf = t & 15, ig = t >> 4; // 16 i-groups
    float s = 0.f;
    for (int i = ig; i < 2048; i += 16) s += part[(size_t)i * 1024 + leaf0 + lf];
    red[t] = s;
    __syncthreads();
    if (t < 16) {
        float a = 0.f;
#pragma unroll
        for (int g = 0; g < 16; ++g) a += red[t + 16 * g];
        Sleaf[leaf0 + t] = a;
    }
}

// ---------------------------------------------------------------------------
// Kernel 4: build node sums up the tree, compute penalty, write out[2097152].
// ---------------------------------------------------------------------------
__global__ __launch_bounds__(256) void k_penalty(const float* __restrict__ Sleaf,
                                                 float* __restrict__ out) {
    __shared__ float S[2047];
    __shared__ float red[4];
    int t = threadIdx.x;
    for (int i = t; i < 1024; i += 256) S[1023 + i] = Sleaf[i];
    __syncthreads();
    for (int L = 9; L >= 0; --L) {
        int o = (1 << L) - 1, n = 1 << L;
        for (int k = t; k < n; k += 256) {
            int gi = o + k;
            S[gi] = S[2 * gi + 1] + S[2 * gi + 2];
        }
        __syncthreads();
    }
    float acc = 0.f;
    for (int gi = 1 + t; gi <= 2046; gi += 256) {
        int lvl = 31 - __clz(gi + 1);          // child tree-layer (1..10)
        float wgt = 0.001f * exp2f((float)(1 - lvl)) * 0.5f; // lamda * 2^-(lvl-1) * 0.5
        float al = S[gi] / S[(gi - 1) >> 1];
        acc -= wgt * (logf(al) + log1pf(-al));
    }
#pragma unroll
    for (int o = 32; o > 0; o >>= 1) acc += __shfl_down(acc, o, 64);
    int lane = t & 63, w = t >> 6;
    if (lane == 0) red[w] = acc;
    __syncthreads();
    if (t == 0)
        out[(size_t)SDT_BATCH * 32] = red[0] + red[1] + red[2] + red[3];
}

extern "C" void kernel_launch(void* const* d_in, const int* in_sizes, int n_in,
                              void* d_out, int out_size, void* d_ws, size_t ws_size,
                              hipStream_t stream) {
    const float* data = (const float*)d_in[0]; // [65536][128]
    const float* Wi   = (const float*)d_in[1]; // [1023][128]
    const float* Wl   = (const float*)d_in[2]; // [32][1024]
    float* out = (float*)d_out;

    unsigned short* p = (unsigned short*)d_ws;                       // 128 MiB
    const size_t P_BYTES = (size_t)SDT_BATCH * SDT_PCOLS * 2;
    float* part  = (float*)((char*)d_ws + P_BYTES);                  // 2048*1024 f32
    float* Sleaf = part + (size_t)2048 * 1024;                       // 1024 f32

    k_gemm1<<<dim3(512, 8), 256, 2 * 128 * 136 * 2, stream>>>(data, Wi, p);
    k_tree<<<2048, 256, 2 * 32 * 516 * 4, stream>>>(p, Wl, out, part);
    k_reduce<<<64, 256, 0, stream>>>(part, Sleaf);
    k_penalty<<<1, 256, 0, stream>>>(Sleaf, out);
}

// Round 2
// 235.663 us; speedup vs baseline: 1.4771x; 1.4771x over previous
//
#include <hip/hip_runtime.h>

typedef float f32x4 __attribute__((ext_vector_type(4)));
typedef short bf16x8 __attribute__((ext_vector_type(8)));

#define SDT_BATCH 65536
#define SDT_PCOLS 1024   // heap layout: node i (0-based Wi row) at col i+1; col 0 unused

__device__ __forceinline__ unsigned short f2bf(float f) {
    union { float f; unsigned int u; } x; x.f = f;
    unsigned int r = (x.u + 0x7fffu + ((x.u >> 16) & 1u)) >> 16;
    return (unsigned short)r;
}
__device__ __forceinline__ float bf2f(unsigned short h) {
    union { unsigned int u; float f; } x; x.u = ((unsigned int)h) << 16;
    return x.f;
}
__device__ __forceinline__ float bfu_lo(unsigned int u) {
    union { unsigned int i; float f; } x; x.i = u << 16; return x.f;
}
__device__ __forceinline__ float bfu_hi(unsigned int u) {
    union { unsigned int i; float f; } x; x.i = u & 0xffff0000u; return x.f;
}

// ---------------------------------------------------------------------------
// k_prep: W_leaf f32 [32][1024] -> bf16
// ---------------------------------------------------------------------------
__global__ __launch_bounds__(256) void k_prep(const float* __restrict__ Wl,
                                              unsigned short* __restrict__ Wlb) {
    int i = blockIdx.x * 256 + threadIdx.x;           // 8192 float4's
    float4 v = ((const float4*)Wl)[i];
    ushort4 w; w.x = f2bf(v.x); w.y = f2bf(v.y); w.z = f2bf(v.z); w.w = f2bf(v.w);
    ((ushort4*)Wlb)[i] = w;
}

// ---------------------------------------------------------------------------
// k_gemm1: p = sigmoid(data @ Wi^T) bf16, heap-shifted (+1 col).
// Swapped-operand MFMA so threads own 4 consecutive p-cols; shuffle fixes the
// odd +1 start -> aligned uint2 stores. XCD-swizzled grid: each XCD owns a
// contiguous bm range, bn varies fastest -> data fetched from HBM once.
// ---------------------------------------------------------------------------
__global__ __launch_bounds__(256) void k_gemm1(const float* __restrict__ data,
                                               const float* __restrict__ Wi,
                                               unsigned short* __restrict__ p) {
    extern __shared__ char smem[];
    unsigned short (*As)[136] = (unsigned short(*)[136])smem;
    unsigned short (*Bs)[136] = (unsigned short(*)[136])(smem + 128 * 136 * 2);
    const int tid = threadIdx.x;
    const int id = blockIdx.x;            // 4096 blocks
    const int xcd = id & 7, loc = id >> 3;
    const int bm = xcd * 64 + (loc >> 3); // [0,512)
    const int bn = loc & 7;               // [0,8)

    // stage A (contiguous 128x128 f32) -> bf16
    const float4* Ag = (const float4*)(data + (size_t)bm * (128 * 128));
#pragma unroll
    for (int i = 0; i < 16; ++i) {
        int idx = tid + 256 * i;
        float4 v = Ag[idx];
        int e = idx << 2, row = e >> 7, col = e & 127;
        ushort4 w; w.x = f2bf(v.x); w.y = f2bf(v.y); w.z = f2bf(v.z); w.w = f2bf(v.w);
        *(ushort4*)&As[row][col] = w;
    }
    // stage B = Wi rows [bn*128, +128), zero-pad row 1023
#pragma unroll
    for (int i = 0; i < 16; ++i) {
        int idx = tid + 256 * i;
        int e = idx << 2, row = e >> 7, col = e & 127;
        int gr = bn * 128 + row;
        float4 v = make_float4(0.f, 0.f, 0.f, 0.f);
        if (gr < 1023) v = *(const float4*)(Wi + (size_t)gr * 128 + col);
        ushort4 w; w.x = f2bf(v.x); w.y = f2bf(v.y); w.z = f2bf(v.z); w.w = f2bf(v.w);
        *(ushort4*)&Bs[row][col] = w;
    }
    __syncthreads();

    const int w = tid >> 6, lane = tid & 63;
    const int wm = (w >> 1) * 64, wn = (w & 1) * 64;
    const int lr = lane & 15, hi = lane >> 4, lk = hi * 8;
    f32x4 acc[4][4] = {};
#pragma unroll
    for (int ks = 0; ks < 4; ++ks) {
        bf16x8 a[4], b[4];
#pragma unroll
        for (int f = 0; f < 4; ++f)
            a[f] = *(const bf16x8*)&As[wm + f * 16 + lr][ks * 32 + lk];
#pragma unroll
        for (int f = 0; f < 4; ++f)
            b[f] = *(const bf16x8*)&Bs[wn + f * 16 + lr][ks * 32 + lk];
        // swapped operands: D "rows" ((lane>>4)*4+r) = n (p col), "cols" (lane&15) = m
#pragma unroll
        for (int fi = 0; fi < 4; ++fi)
#pragma unroll
            for (int fj = 0; fj < 4; ++fj)
                acc[fi][fj] = __builtin_amdgcn_mfma_f32_16x16x32_bf16(b[fj], a[fi], acc[fi][fj], 0, 0, 0);
    }

    // epilogue: sigmoid -> bf16; aligned stores via neighbor shuffle.
    const size_t rb = (size_t)bm * 128;
#pragma unroll
    for (int fi = 0; fi < 4; ++fi) {
        const int m = wm + fi * 16 + lr;
        unsigned short* prow = p + (rb + m) * SDT_PCOLS;
        unsigned short v[4][4];
#pragma unroll
        for (int fj = 0; fj < 4; ++fj)
#pragma unroll
            for (int r = 0; r < 4; ++r) {
                float x = acc[fi][fj][r];
                float s = __builtin_amdgcn_rcpf(1.f + __expf(-x));
                v[fj][r] = f2bf(s);
            }
        int sh[4];
#pragma unroll
        for (int fj = 0; fj < 4; ++fj)
            sh[fj] = __shfl((int)v[fj][3], (lane + 48) & 63, 64);
#pragma unroll
        for (int fj = 0; fj < 4; ++fj) {
            const int n0 = bn * 128 + wn + fj * 16 + hi * 4;
            unsigned short* q = prow + n0;
            if (fj == 0 && hi == 0) {
                // cols 1+n0..3+n0 (col n0 written by previous wave's tail / unused col 0)
                q[1] = v[0][0];
                *(unsigned int*)(q + 2) = (unsigned int)v[0][1] | ((unsigned int)v[0][2] << 16);
            } else {
                unsigned short pv = (unsigned short)(hi == 0 ? sh[fj - 1] : sh[fj]);
                uint2 d;
                d.x = (unsigned int)pv | ((unsigned int)v[fj][0] << 16);
                d.y = (unsigned int)v[fj][1] | ((unsigned int)v[fj][2] << 16);
                *(uint2*)q = d;   // cols n0..3+n0, 8B aligned
            }
            if (fj == 3 && hi == 3) q[4] = v[3][3];   // tail col n0+4 (=wn'+64)
        }
    }
}

// ---------------------------------------------------------------------------
// k_tree: register tree. 512 threads = 32 rows/block (16-lane group per row).
// Levels 0-3 redundant per lane; levels 4-9 in-lane chunk doubling (all p
// reads naturally aligned thanks to heap +1 layout). Leaves -> swizzled LDS
// for column sums + MFMA GEMM2 (out = leaves @ Wl^T, 8-wave K-split).
// ---------------------------------------------------------------------------
__device__ __forceinline__ int lswz(int row, int colbyte) {
    return row * 2048 + (colbyte ^ ((row & 7) << 4) ^ (((colbyte >> 7) & 7) << 4));
}

__global__ __launch_bounds__(512, 4) void k_tree(const unsigned short* __restrict__ p,
                                                 const unsigned short* __restrict__ Wlb,
                                                 float* __restrict__ out,
                                                 float* __restrict__ part) {
    __shared__ __align__(16) unsigned char lds[65536];  // 32 rows x 2048B leaves; pc overlay
    char* lp = (char*)lds;
    const int tid = threadIdx.x;
    const int g = tid >> 4, l = tid & 15;
    const size_t row = (size_t)blockIdx.x * 32 + g;
    const unsigned short* prow = p + row * SDT_PCOLS;

    // phase 1: path product to this lane's level-4 node (heap col 16+l)
    const int node = 16 + l;
    float m0 = 1.f;
#pragma unroll
    for (int k = 3; k >= 0; --k) {
        int anc = node >> (k + 1);
        int b = (node >> k) & 1;
        float pv = bf2f(prow[anc]);
        m0 *= b ? (1.f - pv) : pv;
    }
    float M[32];
    M[0] = m0;
    // L=4 (col 16+l, 1 val)
    { float pv = bf2f(prow[16 + l]);
      float e = M[0] * pv; M[1] = M[0] - e; M[0] = e; }
    // L=5 (cols 32+2l)
    { unsigned int u = *(const unsigned int*)(prow + 32 + 2 * l);
      float e1 = M[1] * bfu_hi(u); M[3] = M[1] - e1; M[2] = e1;
      float e0 = M[0] * bfu_lo(u); M[1] = M[0] - e0; M[0] = e0; }
    // L=6 (cols 64+4l)
    { uint2 u = *(const uint2*)(prow + 64 + 4 * l);
      float pv[4] = { bfu_lo(u.x), bfu_hi(u.x), bfu_lo(u.y), bfu_hi(u.y) };
#pragma unroll
      for (int j = 3; j >= 0; --j) {
          float e = M[j] * pv[j]; M[2 * j + 1] = M[j] - e; M[2 * j] = e;
      } }
    // L=7 (cols 128+8l)
    { uint4 u = *(const uint4*)(prow + 128 + 8 * l);
      float pv[8] = { bfu_lo(u.x), bfu_hi(u.x), bfu_lo(u.y), bfu_hi(u.y),
                      bfu_lo(u.z), bfu_hi(u.z), bfu_lo(u.w), bfu_hi(u.w) };
#pragma unroll
      for (int j = 7; j >= 0; --j) {
          float e = M[j] * pv[j]; M[2 * j + 1] = M[j] - e; M[2 * j] = e;
      } }
    // L=8 (cols 256+16l)
    { uint4 ua = *(const uint4*)(prow + 256 + 16 * l);
      uint4 ub = *(const uint4*)(prow + 256 + 16 * l + 8);
      float pv[16] = { bfu_lo(ua.x), bfu_hi(ua.x), bfu_lo(ua.y), bfu_hi(ua.y),
                       bfu_lo(ua.z), bfu_hi(ua.z), bfu_lo(ua.w), bfu_hi(ua.w),
                       bfu_lo(ub.x), bfu_hi(ub.x), bfu_lo(ub.y), bfu_hi(ub.y),
                       bfu_lo(ub.z), bfu_hi(ub.z), bfu_lo(ub.w), bfu_hi(ub.w) };
#pragma unroll
      for (int j = 15; j >= 0; --j) {
          float e = M[j] * pv[j]; M[2 * j + 1] = M[j] - e; M[2 * j] = e;
      } }

    // phase 3: level 9 (cols 512+32l+j) -> 64 bf16 leaves into swizzled LDS
#pragma unroll
    for (int c = 0; c < 4; ++c) {
        const int j0 = c * 8;
        uint4 u = *(const uint4*)(prow + 512 + 32 * l + j0);
        float pv[8] = { bfu_lo(u.x), bfu_hi(u.x), bfu_lo(u.y), bfu_hi(u.y),
                        bfu_lo(u.z), bfu_hi(u.z), bfu_lo(u.w), bfu_hi(u.w) };
        unsigned int wd[8];
#pragma unroll
        for (int jj = 0; jj < 8; ++jj) {
            float mu = M[j0 + jj];
            float e = mu * pv[jj];
            float o = mu - e;
            wd[jj] = (unsigned int)f2bf(e) | ((unsigned int)f2bf(o) << 16);
        }
        const int cb = 128 * l + 4 * j0;  // byte offset within row (leaf cols 64l+2*j0)
        uint4 w0 = make_uint4(wd[0], wd[1], wd[2], wd[3]);
        uint4 w1 = make_uint4(wd[4], wd[5], wd[6], wd[7]);
        *(uint4*)(lp + lswz(g, cb)) = w0;
        *(uint4*)(lp + lswz(g, cb + 16)) = w1;
    }
    __syncthreads();

    // column sums over this block's 32 rows: thread t owns leaf cols 2t,2t+1
    {
        float s0 = 0.f, s1 = 0.f;
#pragma unroll 8
        for (int r = 0; r < 32; ++r) {
            unsigned int u = *(const unsigned int*)(lp + lswz(r, 4 * tid));
            s0 += bfu_lo(u); s1 += bfu_hi(u);
        }
        float2 s; s.x = s0; s.y = s1;
        *(float2*)(part + (size_t)blockIdx.x * 1024 + 2 * tid) = s;
    }

    // GEMM2: out[32][32] = leaves @ Wlb^T, 8 waves split K=1024 (128 each)
    const int w = tid >> 6, lane = tid & 63;
    const int lr = lane & 15, hi = lane >> 4;
    f32x4 acc[2][2] = {};
#pragma unroll
    for (int ks = 0; ks < 4; ++ks) {
        const int kcol = w * 128 + ks * 32 + hi * 8;
        bf16x8 a[2], b[2];
#pragma unroll
        for (int fi = 0; fi < 2; ++fi)
            a[fi] = *(const bf16x8*)(lp + lswz(fi * 16 + lr, 2 * kcol));
#pragma unroll
        for (int fj = 0; fj < 2; ++fj)
            b[fj] = *(const bf16x8*)(Wlb + (size_t)(fj * 16 + lr) * 1024 + kcol);
#pragma unroll
        for (int fi = 0; fi < 2; ++fi)
#pragma unroll
            for (int fj = 0; fj < 2; ++fj)
                acc[fi][fj] = __builtin_amdgcn_mfma_f32_16x16x32_bf16(a[fi], b[fj], acc[fi][fj], 0, 0, 0);
    }
    __syncthreads();   // all leaf reads done; overlay pc partials
    float* pc = (float*)lds;  // [8][32][32]
#pragma unroll
    for (int fi = 0; fi < 2; ++fi)
#pragma unroll
        for (int fj = 0; fj < 2; ++fj)
#pragma unroll
            for (int r = 0; r < 4; ++r) {
                int mm = fi * 16 + hi * 4 + r;
                int nn = fj * 16 + lr;
                pc[((size_t)w * 32 + mm) * 32 + nn] = acc[fi][fj][r];
            }
    __syncthreads();
    {
        int mm = tid >> 4, nc = (tid & 15) * 2;
        float sx = 0.f, sy = 0.f;
#pragma unroll
        for (int w8 = 0; w8 < 8; ++w8) {
            float2 v = *(const float2*)&pc[((size_t)w8 * 32 + mm) * 32 + nc];
            sx += v.x; sy += v.y;
        }
        float2 s; s.x = sx; s.y = sy;
        *(float2*)(out + ((size_t)blockIdx.x * 32 + mm) * 32 + nc) = s;
    }
}

// ---------------------------------------------------------------------------
// k_reduce: Sleaf[leaf] = sum over 2048 block partials.
// ---------------------------------------------------------------------------
__global__ __launch_bounds__(256) void k_reduce(const float* __restrict__ part,
                                                float* __restrict__ Sleaf) {
    __shared__ float red[256];
    int t = threadIdx.x;
    int leaf0 = blockIdx.x * 16;
    int lf = t & 15, ig = t >> 4;
    float s = 0.f;
    for (int i = ig; i < 2048; i += 16) s += part[(size_t)i * 1024 + leaf0 + lf];
    red[t] = s;
    __syncthreads();
    if (t < 16) {
        float a = 0.f;
#pragma unroll
        for (int gq = 0; gq < 16; ++gq) a += red[t + 16 * gq];
        Sleaf[leaf0 + t] = a;
    }
}

// ---------------------------------------------------------------------------
// k_penalty: node sums up the tree + penalty scalar.
// ---------------------------------------------------------------------------
__global__ __launch_bounds__(256) void k_penalty(const float* __restrict__ Sleaf,
                                                 float* __restrict__ out) {
    __shared__ float S[2047];
    __shared__ float red[4];
    int t = threadIdx.x;
    for (int i = t; i < 1024; i += 256) S[1023 + i] = Sleaf[i];
    __syncthreads();
    for (int L = 9; L >= 0; --L) {
        int o = (1 << L) - 1, n = 1 << L;
        for (int k = t; k < n; k += 256) {
            int gi = o + k;
            S[gi] = S[2 * gi + 1] + S[2 * gi + 2];
        }
        __syncthreads();
    }
    float acc = 0.f;
    for (int gi = 1 + t; gi <= 2046; gi += 256) {
        int lvl = 31 - __clz(gi + 1);
        float wgt = 0.001f * exp2f((float)(1 - lvl)) * 0.5f;
        float al = S[gi] / S[(gi - 1) >> 1];
        acc -= wgt * (logf(al) + log1pf(-al));
    }
#pragma unroll
    for (int o = 32; o > 0; o >>= 1) acc += __shfl_down(acc, o, 64);
    int lane = t & 63, w = t >> 6;
    if (lane == 0) red[w] = acc;
    __syncthreads();
    if (t == 0)
        out[(size_t)SDT_BATCH * 32] = red[0] + red[1] + red[2] + red[3];
}

extern "C" void kernel_launch(void* const* d_in, const int* in_sizes, int n_in,
                              void* d_out, int out_size, void* d_ws, size_t ws_size,
                              hipStream_t stream) {
    const float* data = (const float*)d_in[0]; // [65536][128]
    const float* Wi   = (const float*)d_in[1]; // [1023][128]
    const float* Wl   = (const float*)d_in[2]; // [32][1024]
    float* out = (float*)d_out;

    unsigned short* p = (unsigned short*)d_ws;                 // 128 MiB (+4KB guard after)
    const size_t P_BYTES = (size_t)SDT_BATCH * SDT_PCOLS * 2;
    char* base = (char*)d_ws + P_BYTES + 4096;
    float* part  = (float*)base;                               // 2048*1024 f32 = 8 MiB
    float* Sleaf = (float*)(base + 8388608);                   // 1024 f32 (+pad)
    unsigned short* Wlb = (unsigned short*)(base + 8388608 + 4096);  // 64 KiB

    k_prep<<<32, 256, 0, stream>>>(Wl, Wlb);
    k_gemm1<<<4096, 256, 2 * 128 * 136 * 2, stream>>>(data, Wi, p);
    k_tree<<<2048, 512, 0, stream>>>(p, Wlb, out, part);
    k_reduce<<<64, 256, 0, stream>>>(part, Sleaf);
    k_penalty<<<1, 256, 0, stream>>>(Sleaf, out);
}

// Round 3
// 206.596 us; speedup vs baseline: 1.6850x; 1.1407x over previous
//
#include <hip/hip_runtime.h>

typedef float f32x4 __attribute__((ext_vector_type(4)));
typedef short bf16x8 __attribute__((ext_vector_type(8)));

#define SDT_BATCH 65536

__device__ __forceinline__ unsigned short f2bf(float f) {
    union { float f; unsigned int u; } x; x.f = f;
    unsigned int r = (x.u + 0x7fffu + ((x.u >> 16) & 1u)) >> 16;
    return (unsigned short)r;
}
__device__ __forceinline__ float bf2f(unsigned short h) {
    union { unsigned int u; float f; } x; x.u = ((unsigned int)h) << 16;
    return x.f;
}
__device__ __forceinline__ float bfu_lo(unsigned int u) {
    union { unsigned int i; float f; } x; x.i = u << 16; return x.f;
}
__device__ __forceinline__ float bfu_hi(unsigned int u) {
    union { unsigned int i; float f; } x; x.i = u & 0xffff0000u; return x.f;
}

// swizzled byte offset into the 32-row x 2048B LDS panel (p, later leaves)
__device__ __forceinline__ int lswz(int row, int b) {
    return row * 2048 + (b ^ ((row & 7) << 4) ^ (((b >> 7) & 7) << 4));
}

// ---------------------------------------------------------------------------
// k_prep: Wi [1023][128] f32 -> Wib [1024][128] bf16 (row 1023 zero),
//         Wl [32][1024] f32 -> Wlb bf16.
// ---------------------------------------------------------------------------
__global__ __launch_bounds__(256) void k_prep(const float* __restrict__ Wi,
                                              const float* __restrict__ Wl,
                                              unsigned short* __restrict__ Wib,
                                              unsigned short* __restrict__ Wlb) {
    int i = blockIdx.x * 256 + threadIdx.x;   // 160*256 = 40960 float4 slots
    if (i < 32736) {
        float4 v = ((const float4*)Wi)[i];
        ushort4 w; w.x = f2bf(v.x); w.y = f2bf(v.y); w.z = f2bf(v.z); w.w = f2bf(v.w);
        ((ushort4*)Wib)[i] = w;
    } else if (i < 32768) {
        ushort4 z; z.x = 0; z.y = 0; z.z = 0; z.w = 0;
        ((ushort4*)Wib)[i] = z;               // zero-pad row 1023
    } else {
        float4 v = ((const float4*)Wl)[i - 32768];
        ushort4 w; w.x = f2bf(v.x); w.y = f2bf(v.y); w.z = f2bf(v.z); w.w = f2bf(v.w);
        ((ushort4*)Wlb)[i - 32768] = w;
    }
}

// ---------------------------------------------------------------------------
// k_fused: per 32-row block:
//   phase G: p = sigmoid(data32x128 @ Wib^T) -> LDS (bf16, heap +1 shift,
//            XOR-swizzled). 8 waves, each owns 128 p-cols; Wib streamed from L2.
//   phase T: register tree (16 lanes per row) reading p from LDS; leaves
//            overwrite the p panel (bf16).
//   phase S: per-block leaf column sums -> part; GEMM2 out = leaves @ Wlb^T.
// ---------------------------------------------------------------------------
__global__ __launch_bounds__(512, 4) void k_fused(const float* __restrict__ data,
                                                  const unsigned short* __restrict__ Wib,
                                                  const unsigned short* __restrict__ Wlb,
                                                  float* __restrict__ out,
                                                  float* __restrict__ part) {
    __shared__ __align__(16) char lds[65536 + 8704];
    char* lp = lds;                                           // p / leaves / pc
    unsigned short (*As)[136] = (unsigned short(*)[136])(lds + 65536);
    const int tid = threadIdx.x;
    const int blk = blockIdx.x;

    // ---- stage A: 32x128 f32 -> bf16 LDS ----
    const float4* Ag = (const float4*)(data + (size_t)blk * 32 * 128);
#pragma unroll
    for (int i = 0; i < 2; ++i) {
        int idx = tid + 512 * i;             // 1024 float4
        float4 v = Ag[idx];
        int e = idx << 2, row = e >> 7, col = e & 127;
        ushort4 w; w.x = f2bf(v.x); w.y = f2bf(v.y); w.z = f2bf(v.z); w.w = f2bf(v.w);
        *(ushort4*)&As[row][col] = w;
    }
    __syncthreads();

    const int w = tid >> 6, lane = tid & 63;
    const int lr = lane & 15, hi = lane >> 4;

    // ---- phase G: GEMM M=32 N=1024(K-split by wave: each wave 128 cols) K=128
    f32x4 acc[2][8] = {};
#pragma unroll
    for (int ks = 0; ks < 4; ++ks) {
        bf16x8 a0 = *(const bf16x8*)&As[lr][ks * 32 + hi * 8];
        bf16x8 a1 = *(const bf16x8*)&As[16 + lr][ks * 32 + hi * 8];
#pragma unroll
        for (int fj = 0; fj < 8; ++fj) {
            const unsigned short* bp =
                Wib + (size_t)(w * 128 + fj * 16 + lr) * 128 + ks * 32 + hi * 8;
            bf16x8 b = *(const bf16x8*)bp;
            // swapped operands: D-"row" = n (p col), D-"col" = m (batch row)
            acc[0][fj] = __builtin_amdgcn_mfma_f32_16x16x32_bf16(b, a0, acc[0][fj], 0, 0, 0);
            acc[1][fj] = __builtin_amdgcn_mfma_f32_16x16x32_bf16(b, a1, acc[1][fj], 0, 0, 0);
        }
    }

    // ---- sigmoid -> bf16 -> LDS p (heap-shifted +1, swizzled) ----
#pragma unroll
    for (int fi = 0; fi < 2; ++fi) {
        const int m = fi * 16 + lr;
        int prev = 0;
#pragma unroll
        for (int fj = 0; fj < 8; ++fj) {
            unsigned short v[4];
#pragma unroll
            for (int r = 0; r < 4; ++r) {
                float x = acc[fi][fj][r];
                v[r] = f2bf(__builtin_amdgcn_rcpf(1.f + __expf(-x)));
            }
            int cur = __shfl((int)v[3], (lane + 48) & 63, 64);
            const int n0 = w * 128 + fj * 16 + hi * 4;
            if (fj == 0 && hi == 0) {
                // cols n0+1..n0+3 (col n0 = w*128 written by wave w-1's tail; col 0 unused)
                *(unsigned short*)(lp + lswz(m, 2 * n0 + 2)) = v[0];
                *(unsigned int*)(lp + lswz(m, 2 * n0 + 4)) =
                    (unsigned int)v[1] | ((unsigned int)v[2] << 16);
            } else {
                unsigned short pv = (unsigned short)(hi == 0 ? prev : cur);
                uint2 d;
                d.x = (unsigned int)pv | ((unsigned int)v[0] << 16);
                d.y = (unsigned int)v[1] | ((unsigned int)v[2] << 16);
                *(uint2*)(lp + lswz(m, 2 * n0)) = d;   // cols n0..n0+3
            }
            if (fj == 7 && hi == 3 && w < 7)           // tail col (w+1)*128
                *(unsigned short*)(lp + lswz(m, 2 * (w * 128 + 128))) = v[3];
            prev = cur;
        }
    }
    __syncthreads();

    // ---- phase T: register tree. group g = row, 16 lanes each ----
    const int g = tid >> 4, l = tid & 15;

    // path product to level-4 node (heap col 16+l)
    const int node = 16 + l;
    float m0 = 1.f;
#pragma unroll
    for (int k = 3; k >= 0; --k) {
        int anc = node >> (k + 1);
        int b = (node >> k) & 1;
        float pv = bf2f(*(const unsigned short*)(lp + lswz(g, 2 * anc)));
        m0 *= b ? (1.f - pv) : pv;
    }
    float M[32];
    M[0] = m0;
    // L=4 (col 16+l)
    { float pv = bf2f(*(const unsigned short*)(lp + lswz(g, 32 + 2 * l)));
      float e = M[0] * pv; M[1] = M[0] - e; M[0] = e; }
    // L=5 (cols 32+2l)
    { unsigned int u = *(const unsigned int*)(lp + lswz(g, 64 + 4 * l));
      float e1 = M[1] * bfu_hi(u); M[3] = M[1] - e1; M[2] = e1;
      float e0 = M[0] * bfu_lo(u); M[1] = M[0] - e0; M[0] = e0; }
    // L=6 (cols 64+4l)
    { uint2 u = *(const uint2*)(lp + lswz(g, 128 + 8 * l));
      float pv[4] = { bfu_lo(u.x), bfu_hi(u.x), bfu_lo(u.y), bfu_hi(u.y) };
#pragma unroll
      for (int j = 3; j >= 0; --j) {
          float e = M[j] * pv[j]; M[2 * j + 1] = M[j] - e; M[2 * j] = e;
      } }
    // L=7 (cols 128+8l)
    { uint4 u = *(const uint4*)(lp + lswz(g, 256 + 16 * l));
      float pv[8] = { bfu_lo(u.x), bfu_hi(u.x), bfu_lo(u.y), bfu_hi(u.y),
                      bfu_lo(u.z), bfu_hi(u.z), bfu_lo(u.w), bfu_hi(u.w) };
#pragma unroll
      for (int j = 7; j >= 0; --j) {
          float e = M[j] * pv[j]; M[2 * j + 1] = M[j] - e; M[2 * j] = e;
      } }
    // L=8 (cols 256+16l)
    { uint4 ua = *(const uint4*)(lp + lswz(g, 512 + 32 * l));
      uint4 ub = *(const uint4*)(lp + lswz(g, 512 + 32 * l + 16));
      float pv[16] = { bfu_lo(ua.x), bfu_hi(ua.x), bfu_lo(ua.y), bfu_hi(ua.y),
                       bfu_lo(ua.z), bfu_hi(ua.z), bfu_lo(ua.w), bfu_hi(ua.w),
                       bfu_lo(ub.x), bfu_hi(ub.x), bfu_lo(ub.y), bfu_hi(ub.y),
                       bfu_lo(ub.z), bfu_hi(ub.z), bfu_lo(ub.w), bfu_hi(ub.w) };
#pragma unroll
      for (int j = 15; j >= 0; --j) {
          float e = M[j] * pv[j]; M[2 * j + 1] = M[j] - e; M[2 * j] = e;
      } }

    // L=9: read all 4 uint4 of p first (same row only), then overwrite with leaves
    uint4 u9[4];
#pragma unroll
    for (int c = 0; c < 4; ++c)
        u9[c] = *(const uint4*)(lp + lswz(g, 1024 + 64 * l + 16 * c));
    __builtin_amdgcn_sched_barrier(0);   // keep leaf writes after p reads
#pragma unroll
    for (int c = 0; c < 4; ++c) {
        float pv[8] = { bfu_lo(u9[c].x), bfu_hi(u9[c].x), bfu_lo(u9[c].y), bfu_hi(u9[c].y),
                        bfu_lo(u9[c].z), bfu_hi(u9[c].z), bfu_lo(u9[c].w), bfu_hi(u9[c].w) };
        unsigned int wd[8];
#pragma unroll
        for (int jj = 0; jj < 8; ++jj) {
            float mu = M[8 * c + jj];
            float e = mu * pv[jj];
            float o = mu - e;
            wd[jj] = (unsigned int)f2bf(e) | ((unsigned int)f2bf(o) << 16);
        }
        const int cb = 128 * l + 32 * c;   // leaf byte offset within row
        uint4 w0 = make_uint4(wd[0], wd[1], wd[2], wd[3]);
        uint4 w1 = make_uint4(wd[4], wd[5], wd[6], wd[7]);
        *(uint4*)(lp + lswz(g, cb)) = w0;
        *(uint4*)(lp + lswz(g, cb + 16)) = w1;
    }
    __syncthreads();

    // ---- phase S: column sums over 32 rows (thread t owns leaf cols 2t,2t+1)
    {
        float s0 = 0.f, s1 = 0.f;
#pragma unroll 8
        for (int r = 0; r < 32; ++r) {
            unsigned int u = *(const unsigned int*)(lp + lswz(r, 4 * tid));
            s0 += bfu_lo(u); s1 += bfu_hi(u);
        }
        float2 s; s.x = s0; s.y = s1;
        *(float2*)(part + (size_t)blk * 1024 + 2 * tid) = s;
    }

    // ---- GEMM2: out[32][32] = leaves @ Wlb^T, 8 waves split K=1024 ----
    f32x4 acc2[2][2] = {};
#pragma unroll
    for (int ks = 0; ks < 4; ++ks) {
        const int kcol = w * 128 + ks * 32 + hi * 8;
        bf16x8 a[2], b[2];
#pragma unroll
        for (int fi = 0; fi < 2; ++fi)
            a[fi] = *(const bf16x8*)(lp + lswz(fi * 16 + lr, 2 * kcol));
#pragma unroll
        for (int fj = 0; fj < 2; ++fj)
            b[fj] = *(const bf16x8*)(Wlb + (size_t)(fj * 16 + lr) * 1024 + kcol);
#pragma unroll
        for (int fi = 0; fi < 2; ++fi)
#pragma unroll
            for (int fj = 0; fj < 2; ++fj)
                acc2[fi][fj] = __builtin_amdgcn_mfma_f32_16x16x32_bf16(a[fi], b[fj], acc2[fi][fj], 0, 0, 0);
    }
    __syncthreads();   // all leaf reads done; overlay pc partials
    float* pc = (float*)lds;   // [8][32][32] f32
#pragma unroll
    for (int fi = 0; fi < 2; ++fi)
#pragma unroll
        for (int fj = 0; fj < 2; ++fj)
#pragma unroll
            for (int r = 0; r < 4; ++r) {
                int mm = fi * 16 + hi * 4 + r;
                int nn = fj * 16 + lr;
                pc[((size_t)w * 32 + mm) * 32 + nn] = acc2[fi][fj][r];
            }
    __syncthreads();
    {
        int mm = tid >> 4, nc = (tid & 15) * 2;
        float sx = 0.f, sy = 0.f;
#pragma unroll
        for (int w8 = 0; w8 < 8; ++w8) {
            float2 v = *(const float2*)&pc[((size_t)w8 * 32 + mm) * 32 + nc];
            sx += v.x; sy += v.y;
        }
        float2 s; s.x = sx; s.y = sy;
        *(float2*)(out + ((size_t)blk * 32 + mm) * 32 + nc) = s;
    }
}

// ---------------------------------------------------------------------------
// k_reduce: Sleaf[leaf] = sum over 2048 block partials.
// ---------------------------------------------------------------------------
__global__ __launch_bounds__(256) void k_reduce(const float* __restrict__ part,
                                                float* __restrict__ Sleaf) {
    __shared__ float red[256];
    int t = threadIdx.x;
    int leaf0 = blockIdx.x * 16;
    int lf = t & 15, ig = t >> 4;
    float s = 0.f;
    for (int i = ig; i < 2048; i += 16) s += part[(size_t)i * 1024 + leaf0 + lf];
    red[t] = s;
    __syncthreads();
    if (t < 16) {
        float a = 0.f;
#pragma unroll
        for (int gq = 0; gq < 16; ++gq) a += red[t + 16 * gq];
        Sleaf[leaf0 + t] = a;
    }
}

// ---------------------------------------------------------------------------
// k_penalty: node sums up the tree + penalty scalar.
// ---------------------------------------------------------------------------
__global__ __launch_bounds__(256) void k_penalty(const float* __restrict__ Sleaf,
                                                 float* __restrict__ out) {
    __shared__ float S[2047];
    __shared__ float red[4];
    int t = threadIdx.x;
    for (int i = t; i < 1024; i += 256) S[1023 + i] = Sleaf[i];
    __syncthreads();
    for (int L = 9; L >= 0; --L) {
        int o = (1 << L) - 1, n = 1 << L;
        for (int k = t; k < n; k += 256) {
            int gi = o + k;
            S[gi] = S[2 * gi + 1] + S[2 * gi + 2];
        }
        __syncthreads();
    }
    float acc = 0.f;
    for (int gi = 1 + t; gi <= 2046; gi += 256) {
        int lvl = 31 - __clz(gi + 1);
        float wgt = 0.001f * exp2f((float)(1 - lvl)) * 0.5f;
        float al = S[gi] / S[(gi - 1) >> 1];
        acc -= wgt * (logf(al) + log1pf(-al));
    }
#pragma unroll
    for (int o = 32; o > 0; o >>= 1) acc += __shfl_down(acc, o, 64);
    int lane = t & 63, w = t >> 6;
    if (lane == 0) red[w] = acc;
    __syncthreads();
    if (t == 0)
        out[(size_t)SDT_BATCH * 32] = red[0] + red[1] + red[2] + red[3];
}

extern "C" void kernel_launch(void* const* d_in, const int* in_sizes, int n_in,
                              void* d_out, int out_size, void* d_ws, size_t ws_size,
                              hipStream_t stream) {
    const float* data = (const float*)d_in[0]; // [65536][128]
    const float* Wi   = (const float*)d_in[1]; // [1023][128]
    const float* Wl   = (const float*)d_in[2]; // [32][1024]
    float* out = (float*)d_out;

    unsigned short* Wib = (unsigned short*)d_ws;                     // 256 KiB [1024][128]
    unsigned short* Wlb = (unsigned short*)((char*)d_ws + 262144);   // 64 KiB  [32][1024]
    float* part  = (float*)((char*)d_ws + 327680);                   // 8 MiB [2048][1024]
    float* Sleaf = part + (size_t)2048 * 1024;                       // 1024 f32

    k_prep<<<160, 256, 0, stream>>>(Wi, Wl, Wib, Wlb);
    k_fused<<<2048, 512, 0, stream>>>(data, Wib, Wlb, out, part);
    k_reduce<<<64, 256, 0, stream>>>(part, Sleaf);
    k_penalty<<<1, 256, 0, stream>>>(Sleaf, out);
}